// Round 8
// baseline (172.703 us; speedup 1.0000x reference)
//
#include <hip/hip_runtime.h>

#define G_ 100
#define T_ 24
#define GP1 101
#define TILE (G_ * T_)        // 2400 floats per (b,pass) tile
#define VPB (TILE / 4)        // 600 float4 per tile

typedef float vfloat4 __attribute__((ext_vector_type(4)));

// One block, once: prices + stable rank-sort (== jnp.argsort) into workspace.
__global__ void setup_sort_kernel(const float* __restrict__ b_G,
                                  const float* __restrict__ voll,
                                  const float* __restrict__ vosp,
                                  const float* __restrict__ ru,
                                  const float* __restrict__ rd,
                                  int* __restrict__ order_out,     // [2][101]
                                  float* __restrict__ price_out)   // [2][101]
{
    __shared__ float pu[GP1], pd[GP1];
    int i = threadIdx.x;
    if (i < GP1) {
        if (i < G_) { float bg = b_G[i]; pu[i] = ru[0] * bg; pd[i] = rd[0] * bg; }
        else        { pu[i] = voll[0];   pd[i] = vosp[0]; }
    }
    __syncthreads();
    if (i < GP1) {
        float mu = pu[i], md = pd[i];
        int r0 = 0, r1 = 0;
        for (int j = 0; j < GP1; ++j) {
            float vu = pu[j], vd = pd[j];
            r0 += (vu < mu) || (vu == mu && j < i);
            r1 += (vd < md) || (vd == md && j < i);
        }
        order_out[r0] = i;        price_out[r0] = mu;
        order_out[GP1 + r1] = i;  price_out[GP1 + r1] = md;
    }
}

// Dual-pass merit-order chunk: lanes 0..23 scan the up-tile, 24..47 the
// dn-tile. ord/price are wave-uniform scalar loads, per-lane selected by p.
// caps from LDS (batched ds_reads); alloc stored DIRECTLY to global.
template<int N>
__device__ __forceinline__ void scan_chunk(int k0,
    const float* __restrict__ lds, int p, int t,
    const int* __restrict__ o0, const int* __restrict__ o1,
    const float* __restrict__ q0, const float* __restrict__ q1,
    float* __restrict__ dst,                 // du/dd base for this (b,p): +g*24+t
    float dem, float& before, float& objp, float& slackv)
{
    int gg[N]; float pr[N], cap[N];
#pragma unroll
    for (int j = 0; j < N; ++j) {            // s_load pairs + per-lane select
        int ga = o0[k0 + j], gb = o1[k0 + j];
        float qa = q0[k0 + j], qb = q1[k0 + j];
        gg[j] = p ? gb : ga;
        pr[j] = p ? qb : qa;
    }
#pragma unroll
    for (int j = 0; j < N; ++j) {            // batched LDS cap reads (MLP)
        int gl = (gg[j] < G_) ? gg[j] : 0;   // slack slot: dummy read, own tile
        cap[j] = lds[p * TILE + gl * T_ + t];
    }
#pragma unroll
    for (int j = 0; j < N; ++j) {
        float c = (gg[j] == G_) ? dem : cap[j];
        float a = fminf(fmaxf(dem - before, 0.f), c);
        before += c;
        objp = fmaf(pr[j], a, objp);
        if (gg[j] == G_) slackv = a;
        else             dst[gg[j] * T_] = a;   // direct 96B-row store (R1-proven)
    }
}

__global__ __launch_bounds__(64, 2) void dispatch_kernel(
    const float* __restrict__ R_up, const float* __restrict__ R_dn,
    const float* __restrict__ omega,
    const int* __restrict__ ord_ws, const float* __restrict__ pr_ws,
    float* __restrict__ out, int B)
{
    __shared__ float s_tile[2 * TILE];       // 19200 B -> 8 single-wave blocks/CU

    const int lane = threadIdx.x;            // one wave per block
    const int b    = blockIdx.x;
    const size_t bgt = (size_t)B * TILE;

    // ---- load BOTH tiles (20 float4 insts, 19.2 KB in flight) ----
    vfloat4 bu[10], bd[10];
    {
        const vfloat4* __restrict__ s0 = (const vfloat4*)R_up + (size_t)b * VPB;
        const vfloat4* __restrict__ s1 = (const vfloat4*)R_dn + (size_t)b * VPB;
#pragma unroll
        for (int j = 0; j < 9; ++j) { bu[j] = s0[lane + j * 64]; bd[j] = s1[lane + j * 64]; }
        if (lane < VPB - 576) { bu[9] = s0[lane + 576]; bd[9] = s1[lane + 576]; }
    }
    const int p = (lane >= T_) ? 1 : 0;      // half-wave pass id
    const int t = lane - p * T_;             // 0..23 (garbage for lane>=48, masked)
    float om = 0.f;
    if (lane < 2 * T_) om = omega[(size_t)b * T_ + t];

    // ---- stage to LDS (wave-private; intra-wave ordering is automatic) ----
#pragma unroll
    for (int j = 0; j < 9; ++j) {
        *(vfloat4*)&s_tile[(lane + j * 64) * 4]        = bu[j];
        *(vfloat4*)&s_tile[TILE + (lane + j * 64) * 4] = bd[j];
    }
    if (lane < VPB - 576) {
        *(vfloat4*)&s_tile[(lane + 576) * 4]        = bu[9];
        *(vfloat4*)&s_tile[TILE + (lane + 576) * 4] = bd[9];
    }
    __builtin_amdgcn_wave_barrier();

    // ---- dual-pass merit-order scan (48 active lanes) ----
    const int*   __restrict__ o0 = ord_ws;
    const int*   __restrict__ o1 = ord_ws + GP1;
    const float* __restrict__ q0 = pr_ws;
    const float* __restrict__ q1 = pr_ws + GP1;

    float objp = 0.f;
    if (lane < 2 * T_) {
        const float dem = p ? fmaxf(-om, 0.f) : fmaxf(om, 0.f);
        float* __restrict__ dst = out + (size_t)p * bgt + (size_t)b * TILE + t;
        float before = 0.f, slackv = 0.f;
        scan_chunk<16>( 0, s_tile, p, t, o0, o1, q0, q1, dst, dem, before, objp, slackv);
        scan_chunk<16>(16, s_tile, p, t, o0, o1, q0, q1, dst, dem, before, objp, slackv);
        scan_chunk<16>(32, s_tile, p, t, o0, o1, q0, q1, dst, dem, before, objp, slackv);
        scan_chunk<16>(48, s_tile, p, t, o0, o1, q0, q1, dst, dem, before, objp, slackv);
        scan_chunk<16>(64, s_tile, p, t, o0, o1, q0, q1, dst, dem, before, objp, slackv);
        scan_chunk<16>(80, s_tile, p, t, o0, o1, q0, q1, dst, dem, before, objp, slackv);
        scan_chunk< 5>(96, s_tile, p, t, o0, o1, q0, q1, dst, dem, before, objp, slackv);
        out[2 * bgt + (size_t)p * B * T_ + (size_t)b * T_ + t] = slackv;  // LS/SP
    }

    // ---- rt_obj: one butterfly covers up+dn (lanes>=48 hold 0) ----
#pragma unroll
    for (int off = 32; off; off >>= 1) objp += __shfl_xor(objp, off, 64);
    if (lane == 0)
        out[2 * bgt + 2 * (size_t)B * T_ + b] = objp;
}

extern "C" void kernel_launch(void* const* d_in, const int* in_sizes, int n_in,
                              void* d_out, int out_size, void* d_ws, size_t ws_size,
                              hipStream_t stream)
{
    const float* R_up  = (const float*)d_in[0];
    const float* R_dn  = (const float*)d_in[1];
    const float* omega = (const float*)d_in[2];
    const float* b_G   = (const float*)d_in[3];
    const float* voll  = (const float*)d_in[4];
    const float* vosp  = (const float*)d_in[5];
    const float* ru    = (const float*)d_in[6];
    const float* rd    = (const float*)d_in[7];

    const int B = in_sizes[0] / TILE;
    float* out = (float*)d_out;

    int*   ord_ws = (int*)d_ws;
    float* pr_ws  = (float*)((char*)d_ws + 2 * GP1 * sizeof(int));

    setup_sort_kernel<<<1, 128, 0, stream>>>(b_G, voll, vosp, ru, rd, ord_ws, pr_ws);

    // one single-wave block per b: both passes in-lane
    dispatch_kernel<<<B, 64, 0, stream>>>(
        R_up, R_dn, omega, ord_ws, pr_ws, out, B);
}

// Round 9
// 159.487 us; speedup vs baseline: 1.0829x; 1.0829x over previous
//
#include <hip/hip_runtime.h>

#define G_ 100
#define T_ 24
#define GP1 101
#define TILE (G_ * T_)        // 2400 floats per (b,pass) tile
#define BPB 4                 // b's (waves) per block

typedef float vfloat4 __attribute__((ext_vector_type(4)));

// One block, once: prices + stable rank-sort (== jnp.argsort) into workspace.
// Note: slack price (voll=1000 / vosp=500) > any gen price (<=1.5*50=75),
// so rank 100 is ALWAYS the slack slot; ranks 0..99 are real generators.
__global__ void setup_sort_kernel(const float* __restrict__ b_G,
                                  const float* __restrict__ voll,
                                  const float* __restrict__ vosp,
                                  const float* __restrict__ ru,
                                  const float* __restrict__ rd,
                                  int* __restrict__ order_out,     // [2][101]
                                  float* __restrict__ price_out)   // [2][101]
{
    __shared__ float pu[GP1], pd[GP1];
    int i = threadIdx.x;
    if (i < GP1) {
        if (i < G_) { float bg = b_G[i]; pu[i] = ru[0] * bg; pd[i] = rd[0] * bg; }
        else        { pu[i] = voll[0];   pd[i] = vosp[0]; }
    }
    __syncthreads();
    if (i < GP1) {
        float mu = pu[i], md = pd[i];
        int r0 = 0, r1 = 0;
        for (int j = 0; j < GP1; ++j) {
            float vu = pu[j], vd = pd[j];
            r0 += (vu < mu) || (vu == mu && j < i);
            r1 += (vd < md) || (vd == md && j < i);
        }
        order_out[r0] = i;        price_out[r0] = mu;
        order_out[GP1 + r1] = i;  price_out[GP1 + r1] = md;
    }
}

// Merit-order chunk, straight from global: batch N cap loads (96B rows,
// L3-warm), then serial clip-scan with direct global alloc stores.
template<int N>
__device__ __forceinline__ void scan_chunk(int k0,
    const float* __restrict__ capp,          // R_p[b] + t (per-lane)
    const int* __restrict__ o0, const int* __restrict__ o1,
    const float* __restrict__ q0, const float* __restrict__ q1,
    int p, float* __restrict__ dst,          // out tile base + t
    float dem, float& before, float& objp)
{
    int gg[N]; float pr[N], cap[N];
#pragma unroll
    for (int j = 0; j < N; ++j) {            // scalar ord/price + per-lane select
        int ga = o0[k0 + j], gb = o1[k0 + j];
        float qa = q0[k0 + j], qb = q1[k0 + j];
        gg[j] = p ? gb : ga;
        pr[j] = p ? qb : qa;
    }
#pragma unroll
    for (int j = 0; j < N; ++j) cap[j] = capp[gg[j] * T_];   // N loads in flight
#pragma unroll
    for (int j = 0; j < N; ++j) {
        float a = fminf(fmaxf(dem - before, 0.f), cap[j]);
        before += cap[j];
        objp = fmaf(pr[j], a, objp);
        dst[gg[j] * T_] = a;                 // direct 96B-row store
    }
}

__global__ __launch_bounds__(64 * BPB, 4) void dispatch_kernel(
    const float* __restrict__ R_up, const float* __restrict__ R_dn,
    const float* __restrict__ omega,
    const int* __restrict__ ord_ws, const float* __restrict__ pr_ws,
    float* __restrict__ out, int B)
{
    const int tid  = threadIdx.x;
    const int w    = tid >> 6;
    const int lane = tid & 63;
    const int b    = __builtin_amdgcn_readfirstlane(blockIdx.x * BPB + w);
    const size_t bgt = (size_t)B * TILE;

    const int p = (lane >= T_) ? 1 : 0;      // lanes 0..23 up, 24..47 dn
    const int t = (lane < 2 * T_) ? (lane - p * T_) : 0;

    const int*   __restrict__ o0 = ord_ws;
    const int*   __restrict__ o1 = ord_ws + GP1;
    const float* __restrict__ q0 = pr_ws;
    const float* __restrict__ q1 = pr_ws + GP1;

    float objp = 0.f;
    int kdone = 0;                           // uniform across scan lanes (ballot)
    if (lane < 2 * T_) {
        const float om  = omega[(size_t)b * T_ + t];
        const float dem = p ? fmaxf(-om, 0.f) : fmaxf(om, 0.f);
        const float* __restrict__ capp = (p ? R_dn : R_up) + (size_t)b * TILE + t;
        float* __restrict__ dst = out + (size_t)p * bgt + (size_t)b * TILE + t;

        float before = 0.f;
        bool run = true;
        for (int c = 0; c < 12 && run; ++c) {            // 12 x 8 = 96 rows
            scan_chunk<8>(kdone, capp, o0, o1, q0, q1, p, dst, dem, before, objp);
            kdone += 8;
            run = __any(before < dem);                   // wave-wide saturation?
        }
        if (run) {                                       // tail rows 96..99
            scan_chunk<4>(96, capp, o0, o1, q0, q1, p, dst, dem, before, objp);
            kdone = 100;
        }
        // slack is rank 100: alloc = clip(dem - before_total, 0, dem).
        // Early exit => before >= dem => 0, identical to reference.
        float slackv = fmaxf(dem - before, 0.f);
        float sp = p ? q1[GP1 - 1] : q0[GP1 - 1];        // vosp / voll
        objp = fmaf(sp, slackv, objp);
        out[2 * bgt + (size_t)p * B * T_ + (size_t)b * T_ + t] = slackv;
    }

    // ---- rt_obj: one butterfly covers both passes (idle lanes hold 0) ----
#pragma unroll
    for (int off = 32; off; off >>= 1) objp += __shfl_xor(objp, off, 64);
    if (lane == 0)
        out[2 * bgt + 2 * (size_t)B * T_ + b] = objp;

    // ---- zero-fill rows ord[kdone..99] (exactly the untouched allocs) ----
    const int kz  = __builtin_amdgcn_readfirstlane(kdone);  // lane 0 scanned
    const int rem = 100 - kz;
    if (rem > 0) {
        const int total = rem * 6;                       // 6 float4 per row
#pragma unroll 1
        for (int p2 = 0; p2 < 2; ++p2) {
            float* __restrict__ base = out + (size_t)p2 * bgt + (size_t)b * TILE;
            const int* __restrict__ op = ord_ws + p2 * GP1 + kz;
            for (int idx = lane; idx < total; idx += 64) {
                int rel = idx / 6;
                int j   = idx - rel * 6;
                int g   = op[rel];                       // L1-hot vector load
                *(vfloat4*)(base + g * T_ + j * 4) = (vfloat4)(0.f);
            }
        }
    }
}

extern "C" void kernel_launch(void* const* d_in, const int* in_sizes, int n_in,
                              void* d_out, int out_size, void* d_ws, size_t ws_size,
                              hipStream_t stream)
{
    const float* R_up  = (const float*)d_in[0];
    const float* R_dn  = (const float*)d_in[1];
    const float* omega = (const float*)d_in[2];
    const float* b_G   = (const float*)d_in[3];
    const float* voll  = (const float*)d_in[4];
    const float* vosp  = (const float*)d_in[5];
    const float* ru    = (const float*)d_in[6];
    const float* rd    = (const float*)d_in[7];

    const int B = in_sizes[0] / TILE;
    float* out = (float*)d_out;

    int*   ord_ws = (int*)d_ws;
    float* pr_ws  = (float*)((char*)d_ws + 2 * GP1 * sizeof(int));

    setup_sort_kernel<<<1, 128, 0, stream>>>(b_G, voll, vosp, ru, rd, ord_ws, pr_ws);

    // one wave per b (both passes in-lane), 4 waves per block
    dispatch_kernel<<<B / BPB, 64 * BPB, 0, stream>>>(
        R_up, R_dn, omega, ord_ws, pr_ws, out, B);
}

// Round 10
// 152.587 us; speedup vs baseline: 1.1318x; 1.0452x over previous
//
#include <hip/hip_runtime.h>

#define G_ 100
#define T_ 24
#define GP1 101
#define TILE (G_ * T_)        // 2400 floats per (b,pass) tile
#define VPB (TILE / 4)        // 600 float4 per tile
#define WPB 4                 // waves per block: 2 b's x 2 passes
#define BLOCK (64 * WPB)

typedef float vfloat4 __attribute__((ext_vector_type(4)));

// One block, once: prices + stable rank-sort (== jnp.argsort) into workspace.
// Slack price (voll/vosp) > any gen price, so rank 100 is always the slack.
__global__ void setup_sort_kernel(const float* __restrict__ b_G,
                                  const float* __restrict__ voll,
                                  const float* __restrict__ vosp,
                                  const float* __restrict__ ru,
                                  const float* __restrict__ rd,
                                  int* __restrict__ order_out,     // [2][101]
                                  float* __restrict__ price_out)   // [2][101]
{
    __shared__ float pu[GP1], pd[GP1];
    int i = threadIdx.x;
    if (i < GP1) {
        if (i < G_) { float bg = b_G[i]; pu[i] = ru[0] * bg; pd[i] = rd[0] * bg; }
        else        { pu[i] = voll[0];   pd[i] = vosp[0]; }
    }
    __syncthreads();
    if (i < GP1) {
        float mu = pu[i], md = pd[i];
        int r0 = 0, r1 = 0;
        for (int j = 0; j < GP1; ++j) {
            float vu = pu[j], vd = pd[j];
            r0 += (vu < mu) || (vu == mu && j < i);
            r1 += (vd < md) || (vd == md && j < i);
        }
        order_out[r0] = i;        price_out[r0] = mu;
        order_out[GP1 + r1] = i;  price_out[GP1 + r1] = md;
    }
}

// Merit-order chunk: batch N scattered 96B-row cap loads from global (L3-warm),
// serial clip-scan, allocs written to the wave-private LDS tile column.
template<int N>
__device__ __forceinline__ void scan_chunk(int k0,
    const float* __restrict__ capp,          // R_p[b] + t (per-lane)
    const int* __restrict__ ordp, const float* __restrict__ prp,
    float* __restrict__ ldscol,              // tw + t
    float dem, float& before, float& objp)
{
    int gg[N]; float pr[N], cap[N];
#pragma unroll
    for (int j = 0; j < N; ++j) { gg[j] = ordp[k0 + j]; pr[j] = prp[k0 + j]; }
#pragma unroll
    for (int j = 0; j < N; ++j) cap[j] = capp[gg[j] * T_];   // N loads in flight
#pragma unroll
    for (int j = 0; j < N; ++j) {
        float a = fminf(fmaxf(dem - before, 0.f), cap[j]);
        before += cap[j];
        objp = fmaf(pr[j], a, objp);
        ldscol[gg[j] * T_] = a;              // ds_write, own column
    }
}

__global__ __launch_bounds__(BLOCK, 4) void dispatch_kernel(
    const float* __restrict__ R_up, const float* __restrict__ R_dn,
    const float* __restrict__ omega,
    const int* __restrict__ ord_ws, const float* __restrict__ pr_ws,
    float* __restrict__ out, int B)
{
    __shared__ float s_tile[WPB * TILE];     // 38400 B -> 4 blocks/CU, 16 tiles
    __shared__ float s_obj[WPB];

    const int tid  = threadIdx.x;
    const int w    = tid >> 6;
    const int lane = tid & 63;
    const int b = __builtin_amdgcn_readfirstlane(blockIdx.x * 2 + (w >> 1));
    const int p = __builtin_amdgcn_readfirstlane(w & 1);
    const size_t bgt = (size_t)B * TILE;
    float* __restrict__ tw = &s_tile[w * TILE];   // wave-private tile

    // ---- zero the LDS tile: untouched merit rows must be exactly 0 ----
#pragma unroll
    for (int j = 0; j < 9; ++j) *(vfloat4*)&tw[(lane + j * 64) * 4] = (vfloat4)(0.f);
    if (lane < VPB - 576)       *(vfloat4*)&tw[(lane + 576) * 4]    = (vfloat4)(0.f);

    const int t = (lane < T_) ? lane : 0;    // scan lanes: 0..23
    const int*   __restrict__ ordp = ord_ws + p * GP1;
    const float* __restrict__ prp  = pr_ws  + p * GP1;

    float objp = 0.f;
    if (lane < T_) {
        const float om  = omega[(size_t)b * T_ + t];
        const float dem = p ? fmaxf(-om, 0.f) : fmaxf(om, 0.f);
        const float* __restrict__ capp = (p ? R_dn : R_up) + (size_t)b * TILE + t;
        float* __restrict__ ldscol = tw + t;

        float before = 0.f;
        bool run = true;
        int k = 0;
        for (int c = 0; c < 12 && run; ++c) {            // 12 x 8 = 96 rows
            scan_chunk<8>(k, capp, ordp, prp, ldscol, dem, before, objp);
            k += 8;
            run = __any(before < dem);                   // wave-wide saturation
        }
        if (run)                                         // tail rows 96..99
            scan_chunk<4>(96, capp, ordp, prp, ldscol, dem, before, objp);

        // slack (rank 100): clip(dem - sum_all, 0, dem); early exit => 0.
        float slackv = fmaxf(dem - before, 0.f);
        objp = fmaf(prp[GP1 - 1], slackv, objp);
        out[2 * bgt + (size_t)p * B * T_ + (size_t)b * T_ + t] = slackv;
    }

    // ---- rt_obj partial: butterfly over the wave (idle lanes hold 0) ----
#pragma unroll
    for (int off = 32; off; off >>= 1) objp += __shfl_xor(objp, off, 64);
    if (lane == 0) s_obj[w] = objp;

    // ---- stream the finished tile out: coalesced plain float4 (6.6 TB/s path)
    __builtin_amdgcn_wave_barrier();         // order ds_writes before ds_reads
    {
        vfloat4* __restrict__ dst = (vfloat4*)out + ((size_t)p * B + b) * VPB;
#pragma unroll
        for (int j = 0; j < 9; ++j)
            dst[lane + j * 64] = *(const vfloat4*)&tw[(lane + j * 64) * 4];
        if (lane < VPB - 576)
            dst[lane + 576] = *(const vfloat4*)&tw[(lane + 576) * 4];
    }

    // ---- pair up+dn partials per b (barrier hides under stream-out) ----
    __syncthreads();
    if (tid == 0)
        out[2 * bgt + 2 * (size_t)B * T_ + b]     = s_obj[0] + s_obj[1];
    if (tid == 128)
        out[2 * bgt + 2 * (size_t)B * T_ + b]     = s_obj[2] + s_obj[3];
}

extern "C" void kernel_launch(void* const* d_in, const int* in_sizes, int n_in,
                              void* d_out, int out_size, void* d_ws, size_t ws_size,
                              hipStream_t stream)
{
    const float* R_up  = (const float*)d_in[0];
    const float* R_dn  = (const float*)d_in[1];
    const float* omega = (const float*)d_in[2];
    const float* b_G   = (const float*)d_in[3];
    const float* voll  = (const float*)d_in[4];
    const float* vosp  = (const float*)d_in[5];
    const float* ru    = (const float*)d_in[6];
    const float* rd    = (const float*)d_in[7];

    const int B = in_sizes[0] / TILE;
    float* out = (float*)d_out;

    int*   ord_ws = (int*)d_ws;
    float* pr_ws  = (float*)((char*)d_ws + 2 * GP1 * sizeof(int));

    setup_sort_kernel<<<1, 128, 0, stream>>>(b_G, voll, vosp, ru, rd, ord_ws, pr_ws);

    // 4 waves/block = 2 b's x 2 passes; grid B/2
    dispatch_kernel<<<B / 2, BLOCK, 0, stream>>>(
        R_up, R_dn, omega, ord_ws, pr_ws, out, B);
}